// Round 6
// baseline (136.473 us; speedup 1.0000x reference)
//
#include <hip/hip_runtime.h>
#include <hip/hip_bf16.h>
#include <math.h>
#include <stdint.h>

typedef __attribute__((ext_vector_type(8))) short bf16x8;
typedef __attribute__((ext_vector_type(4))) float f32x4;

__device__ __forceinline__ uint32_t pack2(float a, float b) {
    union { __hip_bfloat162 h2; uint32_t u; } c;
    c.h2 = __float22bfloat162_rn(make_float2(a, b));   // v_cvt_pk_bf16_f32
    return c.u;
}
__device__ __forceinline__ unsigned short f2bf(float f) {
    union { __hip_bfloat16 h; unsigned short u; } c;
    c.h = __float2bfloat16(f);
    return c.u;
}
__device__ __forceinline__ float bf2f(unsigned short h) {
    union { uint32_t u; float f; } c; c.u = ((uint32_t)h) << 16;
    return c.f;
}
__device__ __forceinline__ float silu_f(float x) {
    return x / (1.0f + __expf(-x));
}

// Uniform cardinal cubic B-spline bases on grid g_i = -2.2 + 0.4*i.
// Identical to the reference Cox-de-Boor recursion on this uniform grid.
__device__ __forceinline__ void bspline8(float x, float* __restrict__ b) {
    const float tt = (x + 2.2f) * 2.5f;
#pragma unroll
    for (int v = 0; v < 8; ++v) {
        float y = fabsf(tt - (float)(v + 2));
        float p = fmaxf(2.0f - y, 0.0f);
        float q = fmaxf(1.0f - y, 0.0f);
        b[v] = (p * p * p - 4.0f * q * q * q) * (1.0f / 6.0f);
    }
}

// raw barrier: publish LDS writes, do NOT drain vmcnt (loads stay in flight)
#define LGKMBAR()                                                  \
    do {                                                           \
        asm volatile("s_waitcnt lgkmcnt(0)" ::: "memory");         \
        __builtin_amdgcn_s_barrier();                              \
        asm volatile("" ::: "memory");                             \
    } while (0)

// ---------------------------------------------------------------------------
// prep kernels
// ---------------------------------------------------------------------------
__global__ __launch_bounds__(256) void prep_ftw(const float* __restrict__ ftw,
                                                unsigned short* __restrict__ Wb) {
    const int idx = blockIdx.x * 256 + threadIdx.x;   // 98304 = 128*768
    Wb[idx] = f2bf(ftw[idx]);
}

__global__ __launch_bounds__(256) void prep_bp(const float* __restrict__ bw,
                                               const float* __restrict__ sw,
                                               unsigned short* __restrict__ Bp) {
    const int idx = blockIdx.x * 256 + threadIdx.x;   // 524288 = 128*4096
    const int n = idx >> 12;
    const int k = idx & 4095;
    const int f = k >> 4;
    const int v = k & 15;
    float val = 0.f;
    if (v == 0) val = bw[n * 256 + f];
    else if (v <= 8) val = sw[(size_t)(n * 256 + f) * 8 + (v - 1)];
    Bp[idx] = f2bf(val);
}

// ---------------------------------------------------------------------------
// FT GEMM (bf16 MFMA), BM=128, BK=64, block 512 (8 waves as 2x4; wave 64x32).
// Pipelined: reg prefetch depth 2 + LDS double buffer + RAW barriers
// (lgkmcnt(0) only -> global loads stay in flight across barriers, HBM
// streams continuously instead of barrier-bursty).
// Output transposed bf16: HTb[c][r], c = side*128 + o.  grid (256, 2).
// ---------------------------------------------------------------------------
__global__ __launch_bounds__(512) void ft_mfma(
        const float* __restrict__ stm, const float* __restrict__ nstm,
        const unsigned short* __restrict__ Wb, const float* __restrict__ bias,
        unsigned short* __restrict__ HTb) {
    __shared__ alignas(16) char lds[65536];   // [2] x (smA 16 KB | smB 16 KB)
    const int side = blockIdx.y;
    const float* __restrict__ A = side ? nstm : stm;
    const int r0 = blockIdx.x * 128;
    const int t = threadIdx.x;
    const int lane = t & 63, wid = t >> 6;
    const int wr = wid >> 2, wc = wid & 3;     // 2 x 4 waves
    const int fr = lane & 15;
    const int h = lane >> 4;                   // 0..3
    const int fkb = h * 8;

    // staging split: arow==bcol, ako==bko (elements)
    const int arow = t >> 2, ako = (t & 3) * 16;
    const float* __restrict__ agp = &A[(size_t)(r0 + arow) * 768 + ako];
    const unsigned short* __restrict__ bgp = &Wb[(size_t)arow * 768 + ako];
    const uint32_t soff0 = ((uint32_t)arow * 128u + (uint32_t)ako * 2u) ^
                           ((uint32_t)(arow & 7) << 4);
    const uint32_t soff1 = ((uint32_t)arow * 128u + (uint32_t)(ako + 8) * 2u) ^
                           ((uint32_t)(arow & 7) << 4);

    float4 pa0[4], pa1[4];
    int4 pb0[2], pb1[2];

#define FT_LOAD(PA, PB, k0)                                                    \
    {                                                                          \
        _Pragma("unroll") for (int q = 0; q < 4; ++q)                          \
            PA[q] = *reinterpret_cast<const float4*>(&agp[(k0) + q * 4]);      \
        _Pragma("unroll") for (int q = 0; q < 2; ++q)                          \
            PB[q] = *reinterpret_cast<const int4*>(&bgp[(k0) + q * 8]);        \
    }

#define FT_WRITE(PA, PB, bufi)                                                 \
    {                                                                          \
        char* smA = lds + (bufi) * 32768;                                      \
        char* smB = smA + 16384;                                               \
        int4 w0, w1;                                                           \
        w0.x = (int)pack2(PA[0].x, PA[0].y); w0.y = (int)pack2(PA[0].z, PA[0].w); \
        w0.z = (int)pack2(PA[1].x, PA[1].y); w0.w = (int)pack2(PA[1].z, PA[1].w); \
        w1.x = (int)pack2(PA[2].x, PA[2].y); w1.y = (int)pack2(PA[2].z, PA[2].w); \
        w1.z = (int)pack2(PA[3].x, PA[3].y); w1.w = (int)pack2(PA[3].z, PA[3].w); \
        *reinterpret_cast<int4*>(smA + soff0) = w0;                            \
        *reinterpret_cast<int4*>(smA + soff1) = w1;                            \
        *reinterpret_cast<int4*>(smB + soff0) = PB[0];                         \
        *reinterpret_cast<int4*>(smB + soff1) = PB[1];                         \
    }

    f32x4 acc[4][2];
#pragma unroll
    for (int mt = 0; mt < 4; ++mt)
#pragma unroll
        for (int nt = 0; nt < 2; ++nt) acc[mt][nt] = (f32x4){0.f, 0.f, 0.f, 0.f};

#define FT_MFMA(bufi)                                                          \
    {                                                                          \
        const char* smA = lds + (bufi) * 32768;                                \
        const char* smB = smA + 16384;                                         \
        _Pragma("unroll") for (int ks = 0; ks < 2; ++ks) {                     \
            const int kb = ks * 32 + fkb;                                      \
            bf16x8 a[4], b[2];                                                 \
            _Pragma("unroll") for (int mt = 0; mt < 4; ++mt) {                 \
                uint32_t row = (uint32_t)(wr * 64 + mt * 16 + fr);             \
                uint32_t off = (row * 128u + (uint32_t)kb * 2u) ^              \
                               ((row & 7u) << 4);                              \
                a[mt] = *reinterpret_cast<const bf16x8*>(smA + off);           \
            }                                                                  \
            _Pragma("unroll") for (int nt = 0; nt < 2; ++nt) {                 \
                uint32_t col = (uint32_t)(wc * 32 + nt * 16 + fr);             \
                uint32_t off = (col * 128u + (uint32_t)kb * 2u) ^              \
                               ((col & 7u) << 4);                              \
                b[nt] = *reinterpret_cast<const bf16x8*>(smB + off);           \
            }                                                                  \
            _Pragma("unroll") for (int mt = 0; mt < 4; ++mt)                   \
                _Pragma("unroll") for (int nt = 0; nt < 2; ++nt)               \
                    acc[mt][nt] = __builtin_amdgcn_mfma_f32_16x16x32_bf16(     \
                        a[mt], b[nt], acc[mt][nt], 0, 0, 0);                   \
        }                                                                      \
    }

    // prologue: tiles 0,1 -> regs; tile 0 -> LDS buf0
    FT_LOAD(pa0, pb0, 0);
    FT_LOAD(pa1, pb1, 64);
    FT_WRITE(pa0, pb0, 0);    // compiler inserts counted vmcnt (tile1 in flight)
    LGKMBAR();

#pragma unroll 1
    for (int kk = 0; kk < 6; ++kk) {          // tiles 2kk (buf0) and 2kk+1 (buf1)
        const int kbase = kk * 128;
        if (kk < 5) FT_LOAD(pa0, pb0, kbase + 128);   // tile 2kk+2 in flight
        FT_MFMA(0);                                   // tile 2kk
        FT_WRITE(pa1, pb1, 1);                        // tile 2kk+1 (vmcnt counted)
        LGKMBAR();
        if (kk < 5) FT_LOAD(pa1, pb1, kbase + 192);   // tile 2kk+3 in flight
        FT_MFMA(1);                                   // tile 2kk+1
        if (kk < 5) FT_WRITE(pa0, pb0, 0);            // tile 2kk+2
        LGKMBAR();
    }

    // epilogue: HTb[c][r] bf16, int2 over 4 consecutive rows
#pragma unroll
    for (int nt = 0; nt < 2; ++nt) {
        const int colL = wc * 32 + nt * 16 + fr;
        const float bv = bias[colL];
        const size_t cg = (size_t)(side * 128 + colL) * 32768;
#pragma unroll
        for (int mt = 0; mt < 4; ++mt) {
            const int row = r0 + wr * 64 + mt * 16 + h * 4;
            int2 o;
            o.x = (int)pack2(acc[mt][nt][0] + bv, acc[mt][nt][1] + bv);
            o.y = (int)pack2(acc[mt][nt][2] + bv, acc[mt][nt][3] + bv);
            *reinterpret_cast<int2*>(&HTb[cg + row]) = o;
        }
    }
}

// ---------------------------------------------------------------------------
// KAN1 (bf16 MFMA, expanded A, K=256*16) + fused KAN2 + sigmoid.
// BM=64, K-step=128 (8 features), block 512 (8 waves as 2x4; wave 32x32).
// grid 512 -> 2 blocks/CU, 16 waves/CU.
// ---------------------------------------------------------------------------
__global__ __launch_bounds__(512) void kan1_fused(
        const unsigned short* __restrict__ HTb, // 256 x 32768 bf16 (transposed)
        const unsigned short* __restrict__ Bp,  // 128 x 4096 bf16 (padded)
        const float* __restrict__ w2b,          // 128
        const float* __restrict__ w2s,          // 128 x 8
        float* __restrict__ out) {              // 32768
    __shared__ alignas(16) char lds[49152];   // smP 16 KB | smB 32 KB ; epi: smH
    char* smP = lds;
    char* smB = lds + 16384;
    unsigned short* smH = (unsigned short*)lds;
    const int r0 = blockIdx.x * 64;
    const int t = threadIdx.x;
    const int lane = t & 63, wid = t >> 6;
    const int wr = wid >> 2, wc = wid & 3;     // 2 x 4 waves; wave tile 32x32
    const int fr = lane & 15;
    const int h = lane >> 4;
    const int fkb = h * 8;

    const int xrow = t & 63, xf = t >> 6;      // 1 expansion per thread
    const int bn = t >> 2, bk0 = (t & 3) * 32; // B: 64 B contiguous per thread

    f32x4 acc[2][2];
#pragma unroll
    for (int mt = 0; mt < 2; ++mt)
#pragma unroll
        for (int nt = 0; nt < 2; ++nt) acc[mt][nt] = (f32x4){0.f, 0.f, 0.f, 0.f};

    for (int jb = 0; jb < 256; jb += 8) {
        // expand phi: one (row, feature) pair per thread, coalesced bf16 read
        {
            const float x = bf2f(HTb[(size_t)(jb + xf) * 32768 + r0 + xrow]);
            float bs[8];
            bspline8(x, bs);
            const uint32_t w0 = pack2(silu_f(x), bs[0]);
            const uint32_t w1 = pack2(bs[1], bs[2]);
            const uint32_t w2 = pack2(bs[3], bs[4]);
            const uint32_t w3 = pack2(bs[5], bs[6]);
            const uint32_t w4 = pack2(bs[7], 0.f);
            const uint32_t swz = (uint32_t)(xrow & 15) << 4;
            const uint32_t base = (uint32_t)xrow * 256u + (uint32_t)xf * 32u;
            *reinterpret_cast<int4*>(smP + (base ^ swz)) =
                make_int4((int)w0, (int)w1, (int)w2, (int)w3);
            *reinterpret_cast<int4*>(smP + ((base + 16u) ^ swz)) =
                make_int4((int)w4, 0, 0, 0);
        }
        // stage B tile: 4x int4 per thread
        {
            const int4* bgp = reinterpret_cast<const int4*>(
                &Bp[(size_t)bn * 4096 + jb * 16 + bk0]);
#pragma unroll
            for (int q = 0; q < 4; ++q) {
                int4 w = bgp[q];
                uint32_t off = ((uint32_t)bn * 256u +
                                (uint32_t)(bk0 + q * 8) * 2u) ^
                               ((uint32_t)(bn & 15) << 4);
                *reinterpret_cast<int4*>(smB + off) = w;
            }
        }
        __syncthreads();
        __builtin_amdgcn_s_setprio(1);
#pragma unroll
        for (int ks = 0; ks < 4; ++ks) {
            const int kb = ks * 32 + fkb;
            bf16x8 a[2], b[2];
#pragma unroll
            for (int mt = 0; mt < 2; ++mt) {
                uint32_t row = (uint32_t)(wr * 32 + mt * 16 + fr);
                uint32_t off = (row * 256u + (uint32_t)kb * 2u) ^ ((row & 15u) << 4);
                a[mt] = *reinterpret_cast<const bf16x8*>(smP + off);
            }
#pragma unroll
            for (int nt = 0; nt < 2; ++nt) {
                uint32_t n = (uint32_t)(wc * 32 + nt * 16 + fr);
                uint32_t off = (n * 256u + (uint32_t)kb * 2u) ^ ((n & 15u) << 4);
                b[nt] = *reinterpret_cast<const bf16x8*>(smB + off);
            }
#pragma unroll
            for (int mt = 0; mt < 2; ++mt)
#pragma unroll
                for (int nt = 0; nt < 2; ++nt)
                    acc[mt][nt] = __builtin_amdgcn_mfma_f32_16x16x32_bf16(
                        a[mt], b[nt], acc[mt][nt], 0, 0, 0);
        }
        __builtin_amdgcn_s_setprio(0);
        __syncthreads();
    }
    // stash H2 tile (bf16) into LDS [64][136]
#pragma unroll
    for (int mt = 0; mt < 2; ++mt)
#pragma unroll
        for (int nt = 0; nt < 2; ++nt) {
            const int col = wc * 32 + nt * 16 + fr;
#pragma unroll
            for (int j = 0; j < 4; ++j) {
                const int row = wr * 32 + mt * 16 + h * 4 + j;
                smH[row * 136 + col] = f2bf(acc[mt][nt][j]);
            }
        }
    __syncthreads();
    // fused KAN2: 8 threads per row, 16 cols each, shfl reduce, sigmoid
    const int row = t >> 3, qd = t & 7;
    float sum = 0.f;
#pragma unroll 4
    for (int i = 0; i < 16; ++i) {
        const int j = qd * 16 + ((i + qd * 2) & 15);   // stagger banks
        const float x = bf2f(smH[row * 136 + j]);
        float bs[8];
        bspline8(x, bs);
        const float4 s0 = *reinterpret_cast<const float4*>(&w2s[j * 8]);
        const float4 s1 = *reinterpret_cast<const float4*>(&w2s[j * 8 + 4]);
        float s = silu_f(x) * w2b[j];
        s += bs[0] * s0.x + bs[1] * s0.y + bs[2] * s0.z + bs[3] * s0.w;
        s += bs[4] * s1.x + bs[5] * s1.y + bs[6] * s1.z + bs[7] * s1.w;
        sum += s;
    }
    sum += __shfl_xor(sum, 1, 64);
    sum += __shfl_xor(sum, 2, 64);
    sum += __shfl_xor(sum, 4, 64);
    if (qd == 0) out[r0 + row] = 1.0f / (1.0f + __expf(-sum));
}

// ---------------------------------------------------------------------------
extern "C" void kernel_launch(void* const* d_in, const int* in_sizes, int n_in,
                              void* d_out, int out_size, void* d_ws, size_t ws_size,
                              hipStream_t stream) {
    const float* stm  = (const float*)d_in[0];
    const float* nstm = (const float*)d_in[1];
    const float* ft_w = (const float*)d_in[2];
    const float* ft_b = (const float*)d_in[3];
    const float* k1bw = (const float*)d_in[4];
    const float* k1sw = (const float*)d_in[5];
    const float* k2bw = (const float*)d_in[6];
    const float* k2sw = (const float*)d_in[7];
    float* out = (float*)d_out;

    char* ws = (char*)d_ws;
    unsigned short* HTb = (unsigned short*)ws;                        // 16,777,216 B
    unsigned short* Wb  = (unsigned short*)(ws + 16777216);           //    196,608 B
    unsigned short* Bp  = (unsigned short*)(ws + 16777216 + 196608);  //  1,048,576 B

    prep_ftw<<<384, 256, 0, stream>>>(ft_w, Wb);
    prep_bp<<<2048, 256, 0, stream>>>(k1bw, k1sw, Bp);
    ft_mfma<<<dim3(256, 2), 512, 0, stream>>>(stm, nstm, Wb, ft_b, HTb);
    kan1_fused<<<512, 512, 0, stream>>>(HTb, Bp, k2bw, k2sw, out);
}

// Round 7
// 119.167 us; speedup vs baseline: 1.1452x; 1.1452x over previous
//
#include <hip/hip_runtime.h>
#include <hip/hip_bf16.h>
#include <math.h>
#include <stdint.h>

typedef __attribute__((ext_vector_type(8))) short bf16x8;
typedef __attribute__((ext_vector_type(4))) float f32x4;

__device__ __forceinline__ uint32_t pack2(float a, float b) {
    union { __hip_bfloat162 h2; uint32_t u; } c;
    c.h2 = __float22bfloat162_rn(make_float2(a, b));   // v_cvt_pk_bf16_f32
    return c.u;
}
__device__ __forceinline__ unsigned short f2bf(float f) {
    union { __hip_bfloat16 h; unsigned short u; } c;
    c.h = __float2bfloat16(f);
    return c.u;
}
__device__ __forceinline__ float bf2f(unsigned short h) {
    union { uint32_t u; float f; } c; c.u = ((uint32_t)h) << 16;
    return c.f;
}
__device__ __forceinline__ float silu_f(float x) {
    return x / (1.0f + __expf(-x));
}

// Uniform cardinal cubic B-spline bases on grid g_i = -2.2 + 0.4*i.
// Identical to the reference Cox-de-Boor recursion on this uniform grid.
__device__ __forceinline__ void bspline8(float x, float* __restrict__ b) {
    const float tt = (x + 2.2f) * 2.5f;
#pragma unroll
    for (int v = 0; v < 8; ++v) {
        float y = fabsf(tt - (float)(v + 2));
        float p = fmaxf(2.0f - y, 0.0f);
        float q = fmaxf(1.0f - y, 0.0f);
        b[v] = (p * p * p - 4.0f * q * q * q) * (1.0f / 6.0f);
    }
}

__device__ __forceinline__ void gload16(const void* g, void* l) {
    __builtin_amdgcn_global_load_lds(
        (const __attribute__((address_space(1))) void*)g,
        (__attribute__((address_space(3))) void*)l, 16, 0, 0);
}

// ---------------------------------------------------------------------------
// prep kernels
// ---------------------------------------------------------------------------
__global__ __launch_bounds__(256) void prep_ftw(const float* __restrict__ ftw,
                                                unsigned short* __restrict__ Wb) {
    const int idx = blockIdx.x * 256 + threadIdx.x;   // 98304 = 128*768
    Wb[idx] = f2bf(ftw[idx]);
}

__global__ __launch_bounds__(256) void prep_bp(const float* __restrict__ bw,
                                               const float* __restrict__ sw,
                                               unsigned short* __restrict__ Bp) {
    const int idx = blockIdx.x * 256 + threadIdx.x;   // 524288 = 128*4096
    const int n = idx >> 12;
    const int k = idx & 4095;
    const int f = k >> 4;
    const int v = k & 15;
    float val = 0.f;
    if (v == 0) val = bw[n * 256 + f];
    else if (v <= 8) val = sw[(size_t)(n * 256 + f) * 8 + (v - 1)];
    Bp[idx] = f2bf(val);
}

// ---------------------------------------------------------------------------
// FT GEMM (bf16 MFMA), BM=64, BK=64, block 512 (8 waves as 2x4; wave 32x32).
// global_load_lds staging (A fp32, B bf16), LDS double buffer, counted
// vmcnt(4) -- next tile's 4 DMAs stay in flight across barriers, so HBM
// streams continuously instead of barrier-burst/idle.
// LDS linear dest + inverse-swizzled global source + swizzled read (rule 21):
//   A chunks (16B) XOR (row&15); B chunks XOR (col&7).
// fp32->bf16 cvt happens at LDS->reg fragment load (VALU is idle anyway).
// Output transposed bf16: HTb[c][r], c = side*128 + o.  grid (512, 2).
// ---------------------------------------------------------------------------
__global__ __launch_bounds__(512) void ft_mfma(
        const float* __restrict__ stm, const float* __restrict__ nstm,
        const unsigned short* __restrict__ Wb, const float* __restrict__ bias,
        unsigned short* __restrict__ HTb) {
    __shared__ alignas(16) char lds[65536];  // buf{0,1} x (A 16 KB | B 16 KB)
    const int side = blockIdx.y;
    const float* __restrict__ A = side ? nstm : stm;
    const int r0 = blockIdx.x * 64;
    const int t = threadIdx.x;
    const int lane = t & 63, wid = t >> 6;
    const int wr = wid >> 2, wc = wid & 3;     // 2 x 4 waves; wave tile 32x32
    const int fr = lane & 15;
    const int h = lane >> 4;                   // 0..3

    // ---- staging geometry: per wave 2 A-DMAs + 2 B-DMAs of 1 KB each ----
    // A instr i (=wid*2+q) covers rows i*4..i*4+3 (256 B each), lane l ->
    // row i*4+(l>>4), chunk l&15.  Source pre-swizzled: chunk ^= row&15.
    const int i0 = wid * 2, i1 = wid * 2 + 1;
    const int rA0 = i0 * 4 + h, rA1 = i1 * 4 + h;
    const float* srcA0 = &A[(size_t)(r0 + rA0) * 768 + ((fr ^ (rA0 & 15)) * 4)];
    const float* srcA1 = &A[(size_t)(r0 + rA1) * 768 + ((fr ^ (rA1 & 15)) * 4)];
    // B instr i covers cols i*8..i*8+7 (128 B each), lane l -> col i*8+(l>>3),
    // chunk l&7.  Source pre-swizzled: chunk ^= col&7.
    const int cB0 = i0 * 8 + (lane >> 3), cB1 = i1 * 8 + (lane >> 3);
    const unsigned short* srcB0 =
        &Wb[(size_t)cB0 * 768 + (((lane & 7) ^ (cB0 & 7)) * 8)];
    const unsigned short* srcB1 =
        &Wb[(size_t)cB1 * 768 + (((lane & 7) ^ (cB1 & 7)) * 8)];

#define FT_STAGE(bufi, k0)                                                     \
    {                                                                          \
        char* dA = lds + (bufi) * 32768;                                       \
        char* dB = dA + 16384;                                                 \
        gload16(srcA0 + (k0), dA + i0 * 1024);                                 \
        gload16(srcA1 + (k0), dA + i1 * 1024);                                 \
        gload16(srcB0 + (k0), dB + i0 * 1024);                                 \
        gload16(srcB1 + (k0), dB + i1 * 1024);                                 \
    }

    f32x4 acc[2][2];
#pragma unroll
    for (int mt = 0; mt < 2; ++mt)
#pragma unroll
        for (int nt = 0; nt < 2; ++nt) acc[mt][nt] = (f32x4){0.f, 0.f, 0.f, 0.f};

#define FT_COMPUTE(bufi)                                                       \
    {                                                                          \
        const char* bA = lds + (bufi) * 32768;                                 \
        const char* bB = bA + 16384;                                           \
        _Pragma("unroll") for (int ks = 0; ks < 2; ++ks) {                     \
            bf16x8 a[2], b[2];                                                 \
            _Pragma("unroll") for (int mt = 0; mt < 2; ++mt) {                 \
                const uint32_t row = (uint32_t)(wr * 32 + mt * 16 + fr);       \
                const uint32_t c0 = (uint32_t)(ks * 8 + h * 2);                \
                const float4 f0 = *reinterpret_cast<const float4*>(            \
                    bA + row * 256u + ((c0 ^ (uint32_t)fr) << 4));             \
                const float4 f1 = *reinterpret_cast<const float4*>(            \
                    bA + row * 256u + (((c0 + 1) ^ (uint32_t)fr) << 4));       \
                union { bf16x8 v; uint32_t u[4]; } av;                         \
                av.u[0] = pack2(f0.x, f0.y); av.u[1] = pack2(f0.z, f0.w);      \
                av.u[2] = pack2(f1.x, f1.y); av.u[3] = pack2(f1.z, f1.w);      \
                a[mt] = av.v;                                                  \
            }                                                                  \
            _Pragma("unroll") for (int nt = 0; nt < 2; ++nt) {                 \
                const uint32_t col = (uint32_t)(wc * 32 + nt * 16 + fr);       \
                const uint32_t cb = (uint32_t)(ks * 4 + h);                    \
                b[nt] = *reinterpret_cast<const bf16x8*>(                      \
                    bB + col * 128u + ((cb ^ (uint32_t)(fr & 7)) << 4));       \
            }                                                                  \
            _Pragma("unroll") for (int mt = 0; mt < 2; ++mt)                   \
                _Pragma("unroll") for (int nt = 0; nt < 2; ++nt)               \
                    acc[mt][nt] = __builtin_amdgcn_mfma_f32_16x16x32_bf16(     \
                        a[mt], b[nt], acc[mt][nt], 0, 0, 0);                   \
        }                                                                      \
    }

#define WAIT_VM4_BAR()                                                \
    asm volatile("s_waitcnt vmcnt(4)" ::: "memory");                  \
    __builtin_amdgcn_sched_barrier(0);                                \
    __builtin_amdgcn_s_barrier();
#define WAIT_VM0_BAR()                                                \
    asm volatile("s_waitcnt vmcnt(0)" ::: "memory");                  \
    __builtin_amdgcn_sched_barrier(0);                                \
    __builtin_amdgcn_s_barrier();
#define LGKM_BAR()                                                    \
    asm volatile("s_waitcnt lgkmcnt(0)" ::: "memory");                \
    __builtin_amdgcn_sched_barrier(0);                                \
    __builtin_amdgcn_s_barrier();

    // prologue: tile 0 -> buf0
    FT_STAGE(0, 0);
    // main: tiles t (buf t&1); stage t+1 before computing t; vmcnt stays >0
#pragma unroll 1
    for (int tp = 0; tp < 5; ++tp) {          // tile pairs (0,1)..(8,9)
        const int k0 = tp * 128;
        FT_STAGE(1, k0 + 64);
        WAIT_VM4_BAR();                        // buf0 ready, buf1 in flight
        FT_COMPUTE(0);
        LGKM_BAR();                            // my reads done; buf0 reusable
        FT_STAGE(0, k0 + 128);
        WAIT_VM4_BAR();                        // buf1 ready, buf0 in flight
        FT_COMPUTE(1);
        LGKM_BAR();
    }
    // tail: tiles 10 (buf0, staged) and 11
    FT_STAGE(1, 11 * 64);
    WAIT_VM4_BAR();
    FT_COMPUTE(0);
    LGKM_BAR();
    WAIT_VM0_BAR();
    FT_COMPUTE(1);

    // epilogue: HTb[c][r] bf16, int2 over 4 consecutive rows
#pragma unroll
    for (int nt = 0; nt < 2; ++nt) {
        const int colL = wc * 32 + nt * 16 + fr;
        const float bv = bias[colL];
        const size_t cg = (size_t)(side * 128 + colL) * 32768;
#pragma unroll
        for (int mt = 0; mt < 2; ++mt) {
            const int row = r0 + wr * 32 + mt * 16 + h * 4;
            int2 o;
            o.x = (int)pack2(acc[mt][nt][0] + bv, acc[mt][nt][1] + bv);
            o.y = (int)pack2(acc[mt][nt][2] + bv, acc[mt][nt][3] + bv);
            *reinterpret_cast<int2*>(&HTb[cg + row]) = o;
        }
    }
}

// ---------------------------------------------------------------------------
// KAN1 (bf16 MFMA, expanded A, K=256*16) + fused KAN2 + sigmoid.
// BM=64, K-step=128 (8 features), block 512 (8 waves as 2x4; wave 32x32).
// grid 512 -> 2 blocks/CU, 16 waves/CU.
// ---------------------------------------------------------------------------
__global__ __launch_bounds__(512) void kan1_fused(
        const unsigned short* __restrict__ HTb, // 256 x 32768 bf16 (transposed)
        const unsigned short* __restrict__ Bp,  // 128 x 4096 bf16 (padded)
        const float* __restrict__ w2b,          // 128
        const float* __restrict__ w2s,          // 128 x 8
        float* __restrict__ out) {              // 32768
    __shared__ alignas(16) char lds[49152];   // smP 16 KB | smB 32 KB ; epi: smH
    char* smP = lds;
    char* smB = lds + 16384;
    unsigned short* smH = (unsigned short*)lds;
    const int r0 = blockIdx.x * 64;
    const int t = threadIdx.x;
    const int lane = t & 63, wid = t >> 6;
    const int wr = wid >> 2, wc = wid & 3;     // 2 x 4 waves; wave tile 32x32
    const int fr = lane & 15;
    const int h = lane >> 4;
    const int fkb = h * 8;

    const int xrow = t & 63, xf = t >> 6;      // 1 expansion per thread
    const int bn = t >> 2, bk0 = (t & 3) * 32; // B: 64 B contiguous per thread

    f32x4 acc[2][2];
#pragma unroll
    for (int mt = 0; mt < 2; ++mt)
#pragma unroll
        for (int nt = 0; nt < 2; ++nt) acc[mt][nt] = (f32x4){0.f, 0.f, 0.f, 0.f};

    for (int jb = 0; jb < 256; jb += 8) {
        // expand phi: one (row, feature) pair per thread, coalesced bf16 read
        {
            const float x = bf2f(HTb[(size_t)(jb + xf) * 32768 + r0 + xrow]);
            float bs[8];
            bspline8(x, bs);
            const uint32_t w0 = pack2(silu_f(x), bs[0]);
            const uint32_t w1 = pack2(bs[1], bs[2]);
            const uint32_t w2 = pack2(bs[3], bs[4]);
            const uint32_t w3 = pack2(bs[5], bs[6]);
            const uint32_t w4 = pack2(bs[7], 0.f);
            const uint32_t swz = (uint32_t)(xrow & 15) << 4;
            const uint32_t base = (uint32_t)xrow * 256u + (uint32_t)xf * 32u;
            *reinterpret_cast<int4*>(smP + (base ^ swz)) =
                make_int4((int)w0, (int)w1, (int)w2, (int)w3);
            *reinterpret_cast<int4*>(smP + ((base + 16u) ^ swz)) =
                make_int4((int)w4, 0, 0, 0);
        }
        // stage B tile: 4x int4 per thread
        {
            const int4* bgp = reinterpret_cast<const int4*>(
                &Bp[(size_t)bn * 4096 + jb * 16 + bk0]);
#pragma unroll
            for (int q = 0; q < 4; ++q) {
                int4 w = bgp[q];
                uint32_t off = ((uint32_t)bn * 256u +
                                (uint32_t)(bk0 + q * 8) * 2u) ^
                               ((uint32_t)(bn & 15) << 4);
                *reinterpret_cast<int4*>(smB + off) = w;
            }
        }
        __syncthreads();
        __builtin_amdgcn_s_setprio(1);
#pragma unroll
        for (int ks = 0; ks < 4; ++ks) {
            const int kb = ks * 32 + fkb;
            bf16x8 a[2], b[2];
#pragma unroll
            for (int mt = 0; mt < 2; ++mt) {
                uint32_t row = (uint32_t)(wr * 32 + mt * 16 + fr);
                uint32_t off = (row * 256u + (uint32_t)kb * 2u) ^ ((row & 15u) << 4);
                a[mt] = *reinterpret_cast<const bf16x8*>(smP + off);
            }
#pragma unroll
            for (int nt = 0; nt < 2; ++nt) {
                uint32_t n = (uint32_t)(wc * 32 + nt * 16 + fr);
                uint32_t off = (n * 256u + (uint32_t)kb * 2u) ^ ((n & 15u) << 4);
                b[nt] = *reinterpret_cast<const bf16x8*>(smB + off);
            }
#pragma unroll
            for (int mt = 0; mt < 2; ++mt)
#pragma unroll
                for (int nt = 0; nt < 2; ++nt)
                    acc[mt][nt] = __builtin_amdgcn_mfma_f32_16x16x32_bf16(
                        a[mt], b[nt], acc[mt][nt], 0, 0, 0);
        }
        __builtin_amdgcn_s_setprio(0);
        __syncthreads();
    }
    // stash H2 tile (bf16) into LDS [64][136]
#pragma unroll
    for (int mt = 0; mt < 2; ++mt)
#pragma unroll
        for (int nt = 0; nt < 2; ++nt) {
            const int col = wc * 32 + nt * 16 + fr;
#pragma unroll
            for (int j = 0; j < 4; ++j) {
                const int row = wr * 32 + mt * 16 + h * 4 + j;
                smH[row * 136 + col] = f2bf(acc[mt][nt][j]);
            }
        }
    __syncthreads();
    // fused KAN2: 8 threads per row, 16 cols each, shfl reduce, sigmoid
    const int row = t >> 3, qd = t & 7;
    float sum = 0.f;
#pragma unroll 4
    for (int i = 0; i < 16; ++i) {
        const int j = qd * 16 + ((i + qd * 2) & 15);   // stagger banks
        const float x = bf2f(smH[row * 136 + j]);
        float bs[8];
        bspline8(x, bs);
        const float4 s0 = *reinterpret_cast<const float4*>(&w2s[j * 8]);
        const float4 s1 = *reinterpret_cast<const float4*>(&w2s[j * 8 + 4]);
        float s = silu_f(x) * w2b[j];
        s += bs[0] * s0.x + bs[1] * s0.y + bs[2] * s0.z + bs[3] * s0.w;
        s += bs[4] * s1.x + bs[5] * s1.y + bs[6] * s1.z + bs[7] * s1.w;
        sum += s;
    }
    sum += __shfl_xor(sum, 1, 64);
    sum += __shfl_xor(sum, 2, 64);
    sum += __shfl_xor(sum, 4, 64);
    if (qd == 0) out[r0 + row] = 1.0f / (1.0f + __expf(-sum));
}

// ---------------------------------------------------------------------------
extern "C" void kernel_launch(void* const* d_in, const int* in_sizes, int n_in,
                              void* d_out, int out_size, void* d_ws, size_t ws_size,
                              hipStream_t stream) {
    const float* stm  = (const float*)d_in[0];
    const float* nstm = (const float*)d_in[1];
    const float* ft_w = (const float*)d_in[2];
    const float* ft_b = (const float*)d_in[3];
    const float* k1bw = (const float*)d_in[4];
    const float* k1sw = (const float*)d_in[5];
    const float* k2bw = (const float*)d_in[6];
    const float* k2sw = (const float*)d_in[7];
    float* out = (float*)d_out;

    char* ws = (char*)d_ws;
    unsigned short* HTb = (unsigned short*)ws;                        // 16,777,216 B
    unsigned short* Wb  = (unsigned short*)(ws + 16777216);           //    196,608 B
    unsigned short* Bp  = (unsigned short*)(ws + 16777216 + 196608);  //  1,048,576 B

    prep_ftw<<<384, 256, 0, stream>>>(ft_w, Wb);
    prep_bp<<<2048, 256, 0, stream>>>(k1bw, k1sw, Bp);
    ft_mfma<<<dim3(512, 2), 512, 0, stream>>>(stm, nstm, Wb, ft_b, HTb);
    kan1_fused<<<512, 512, 0, stream>>>(HTb, Bp, k2bw, k2sw, out);
}